// Round 2
// baseline (267.173 us; speedup 1.0000x reference)
//
#include <hip/hip_runtime.h>
#include <math.h>

#define NUM_CLASSES 10

// d_ws layout: uint counts[10] | float sum_log | float sumsq   (12 * 4 B)

// NOTE (R1 post-mortem): harness passes integer inputs as int32 regardless of
// the reference's int64 — casting d_in[1] to long long* read 2x past the
// buffer and core-dumped. target is const int*.

__global__ void __launch_bounds__(256) hist_kernel(const int* __restrict__ target,
                                                   unsigned int* __restrict__ counts,
                                                   int n) {
    unsigned int cnt[NUM_CLASSES];
#pragma unroll
    for (int c = 0; c < NUM_CLASSES; ++c) cnt[c] = 0u;

    const int tid = blockIdx.x * blockDim.x + threadIdx.x;
    const int stride = gridDim.x * blockDim.x;
    const int4* __restrict__ t4 = (const int4*)target;  // 4 int32 targets per load
    const int n4 = n >> 2;  // N = 2^22, divisible by 4

    for (int i = tid; i < n4; i += stride) {
        int4 v = t4[i];
#pragma unroll
        for (int c = 0; c < NUM_CLASSES; ++c) {
            cnt[c] += (unsigned int)(v.x == c) + (unsigned int)(v.y == c) +
                      (unsigned int)(v.z == c) + (unsigned int)(v.w == c);
        }
    }

    // wave(64) shuffle reduction per counter
#pragma unroll
    for (int c = 0; c < NUM_CLASSES; ++c) {
        unsigned int v = cnt[c];
        for (int off = 32; off > 0; off >>= 1)
            v += (unsigned int)__shfl_down((int)v, off, 64);
        cnt[c] = v;
    }

    __shared__ unsigned int sh[NUM_CLASSES];
    if (threadIdx.x < NUM_CLASSES) sh[threadIdx.x] = 0u;
    __syncthreads();
    if ((threadIdx.x & 63) == 0) {
#pragma unroll
        for (int c = 0; c < NUM_CLASSES; ++c)
            atomicAdd(&sh[c], cnt[c]);
    }
    __syncthreads();
    if (threadIdx.x < NUM_CLASSES)
        atomicAdd(&counts[threadIdx.x], sh[threadIdx.x]);
}

__global__ void __launch_bounds__(256) main_kernel(const float* __restrict__ outputs,
                                                   const unsigned int* __restrict__ counts_u,
                                                   float* __restrict__ acc,  // [0]=sum_log [1]=sumsq
                                                   int n) {
    float w[NUM_CLASSES];
#pragma unroll
    for (int c = 0; c < NUM_CLASSES; ++c) w[c] = (float)counts_u[c];

    const int tid = blockIdx.x * blockDim.x + threadIdx.x;
    const int stride = gridDim.x * blockDim.x;
    const int npairs = n >> 1;  // 2 rows (20 floats = 5 float4, 16B-aligned) per iter
    const float4* __restrict__ o4 = (const float4*)outputs;

    float sum_log = 0.f, sumsq = 0.f;
    for (int p = tid; p < npairs; p += stride) {
        const float4* base = o4 + (size_t)p * 5;
        float4 a = base[0];
        float4 b = base[1];
        float4 c4 = base[2];
        float4 d = base[3];
        float4 e = base[4];
        float r0[NUM_CLASSES] = {a.x, a.y, a.z, a.w, b.x, b.y, b.z, b.w, c4.x, c4.y};
        float r1[NUM_CLASSES] = {c4.z, c4.w, d.x, d.y, d.z, d.w, e.x, e.y, e.z, e.w};
        float nom0 = 0.f, nom1 = 0.f;
#pragma unroll
        for (int c = 0; c < NUM_CLASSES; ++c) {
            nom0 += r0[c] * w[c];
            nom1 += r1[c] * w[c];
            sumsq += r0[c] * r0[c] + r1[c] * r1[c];
        }
        sum_log += __logf(nom0) + __logf(nom1);
    }

    // wave reduce
    for (int off = 32; off > 0; off >>= 1) {
        sum_log += __shfl_down(sum_log, off, 64);
        sumsq   += __shfl_down(sumsq, off, 64);
    }
    __shared__ float s1[4], s2[4];
    const int wave = threadIdx.x >> 6;
    if ((threadIdx.x & 63) == 0) { s1[wave] = sum_log; s2[wave] = sumsq; }
    __syncthreads();
    if (threadIdx.x == 0) {
        float t1 = 0.f, t2 = 0.f;
        for (int wv = 0; wv < 4; ++wv) { t1 += s1[wv]; t2 += s2[wv]; }
        atomicAdd(&acc[0], t1);
        atomicAdd(&acc[1], t2);
    }
}

__global__ void finalize_kernel(const float* __restrict__ acc, float* __restrict__ out, float fn) {
    if (threadIdx.x == 0 && blockIdx.x == 0) {
        // mean(-log(nom/denom)) = 0.5*log(sumsq) + 0.5*log(N) - sum_log/N
        out[0] = 0.5f * logf(acc[1]) + 0.5f * logf(fn) - acc[0] / fn;
    }
}

extern "C" void kernel_launch(void* const* d_in, const int* in_sizes, int n_in,
                              void* d_out, int out_size, void* d_ws, size_t ws_size,
                              hipStream_t stream) {
    const float* outputs = (const float*)d_in[0];
    const int* target = (const int*)d_in[1];
    const int n = in_sizes[1];  // N samples

    unsigned int* counts = (unsigned int*)d_ws;
    float* acc = (float*)((char*)d_ws + NUM_CLASSES * sizeof(unsigned int));

    hipMemsetAsync(d_ws, 0, (NUM_CLASSES + 2) * sizeof(unsigned int), stream);
    hist_kernel<<<512, 256, 0, stream>>>(target, counts, n);
    main_kernel<<<2048, 256, 0, stream>>>(outputs, counts, acc, n);
    finalize_kernel<<<1, 64, 0, stream>>>(acc, (float*)d_out, (float)n);
}

// Round 3
// 250.303 us; speedup vs baseline: 1.0674x; 1.0674x over previous
//
#include <hip/hip_runtime.h>
#include <math.h>

#define NUM_CLASSES 10
#define A_BLOCKS 512
#define B_BLOCKS 2048

// ws layout (no memset needed — every used word is fully overwritten each call):
//   [0)                : unsigned pc[A_BLOCKS][NUM_CLASSES]   per-block histograms (20480 B)
//   [20480)            : float2   pacc[B_BLOCKS]              per-block {sum_log, sumsq} (16384 B)
// No global atomics anywhere; kernel-boundary coherence orders producer/consumer.

__global__ void __launch_bounds__(256) hist_kernel(const int* __restrict__ target,
                                                   unsigned int* __restrict__ pc, int n) {
    unsigned int cnt[NUM_CLASSES];
#pragma unroll
    for (int c = 0; c < NUM_CLASSES; ++c) cnt[c] = 0u;

    const int tid = blockIdx.x * blockDim.x + threadIdx.x;
    const int stride = gridDim.x * blockDim.x;
    const int4* __restrict__ t4 = (const int4*)target;  // harness passes int32 targets
    const int n4 = n >> 2;

    for (int i = tid; i < n4; i += stride) {
        int4 v = t4[i];
#pragma unroll
        for (int c = 0; c < NUM_CLASSES; ++c) {
            cnt[c] += (unsigned int)(v.x == c) + (unsigned int)(v.y == c) +
                      (unsigned int)(v.z == c) + (unsigned int)(v.w == c);
        }
    }

#pragma unroll
    for (int c = 0; c < NUM_CLASSES; ++c) {
        unsigned int v = cnt[c];
        for (int off = 32; off > 0; off >>= 1)
            v += (unsigned int)__shfl_down((int)v, off, 64);
        cnt[c] = v;
    }

    __shared__ unsigned int sh[4][NUM_CLASSES];
    const int wave = threadIdx.x >> 6;
    if ((threadIdx.x & 63) == 0) {
#pragma unroll
        for (int c = 0; c < NUM_CLASSES; ++c) sh[wave][c] = cnt[c];
    }
    __syncthreads();
    if (threadIdx.x < NUM_CLASSES) {
        const int c = threadIdx.x;
        pc[blockIdx.x * NUM_CLASSES + c] = sh[0][c] + sh[1][c] + sh[2][c] + sh[3][c];
    }
}

__global__ void __launch_bounds__(256) main_kernel(const float* __restrict__ outputs,
                                                   const unsigned int* __restrict__ pc,
                                                   float2* __restrict__ pacc, int n) {
    const int wave = threadIdx.x >> 6;
    const int lane = threadIdx.x & 63;

    // ---- phase 1: reduce per-block histograms -> w[10] (block-local) ----
    unsigned int pw[NUM_CLASSES];
#pragma unroll
    for (int c = 0; c < NUM_CLASSES; ++c) pw[c] = 0u;
#pragma unroll
    for (int r = 0; r < A_BLOCKS / 256; ++r) {
        const unsigned int* row = pc + (threadIdx.x + r * 256) * NUM_CLASSES;
#pragma unroll
        for (int c = 0; c < NUM_CLASSES; ++c) pw[c] += row[c];
    }
#pragma unroll
    for (int c = 0; c < NUM_CLASSES; ++c) {
        unsigned int v = pw[c];
        for (int off = 32; off > 0; off >>= 1)
            v += (unsigned int)__shfl_down((int)v, off, 64);
        pw[c] = v;
    }
    __shared__ unsigned int shw[4][NUM_CLASSES];
    __shared__ float fw[NUM_CLASSES];
    if (lane == 0) {
#pragma unroll
        for (int c = 0; c < NUM_CLASSES; ++c) shw[wave][c] = pw[c];
    }
    __syncthreads();
    if (threadIdx.x < NUM_CLASSES) {
        const int c = threadIdx.x;
        fw[c] = (float)(shw[0][c] + shw[1][c] + shw[2][c] + shw[3][c]);
    }
    __syncthreads();
    float w[NUM_CLASSES];
#pragma unroll
    for (int c = 0; c < NUM_CLASSES; ++c) w[c] = fw[c];

    // ---- phase 2: stream outputs, coalesced via per-wave LDS staging ----
    // chunk = 64 row-pairs = 128 rows = 320 float4 = 5120 B per wave
    __shared__ float4 stage4[4][320];  // 20 KiB
    const float4* __restrict__ o4 = (const float4*)outputs;
    const int nchunks = n >> 7;                    // n/128
    const int nwaves = gridDim.x * 4;
    const int gwave = blockIdx.x * 4 + wave;
    const int iters = (nchunks + nwaves - 1) / nwaves;  // block-uniform trip count

    float sum_log = 0.f, sumsq = 0.f;
    for (int it = 0; it < iters; ++it) {
        const int ch = gwave + it * nwaves;
        const bool valid = ch < nchunks;
        float4 v0, v1, v2, v3, v4;
        if (valid) {
            const size_t b4 = (size_t)ch * 320;
            v0 = o4[b4 + 0 * 64 + lane];   // each: 64 consecutive float4 = 1 KiB coalesced
            v1 = o4[b4 + 1 * 64 + lane];
            v2 = o4[b4 + 2 * 64 + lane];
            v3 = o4[b4 + 3 * 64 + lane];
            v4 = o4[b4 + 4 * 64 + lane];
        }
        __syncthreads();  // prior iteration's LDS reads done before overwrite
        if (valid) {
            stage4[wave][0 * 64 + lane] = v0;
            stage4[wave][1 * 64 + lane] = v1;
            stage4[wave][2 * 64 + lane] = v2;
            stage4[wave][3 * 64 + lane] = v3;
            stage4[wave][4 * 64 + lane] = v4;
        }
        __syncthreads();  // stores visible before cross-lane readback
        if (valid) {
            // lane's row-pair: 20 floats at byte offset lane*80 (16B aligned -> 5x b128)
            const float4* sp = (const float4*)((const float*)&stage4[wave][0] + lane * 20);
            float4 a = sp[0], b = sp[1], c4 = sp[2], d = sp[3], e = sp[4];
            float r0[NUM_CLASSES] = {a.x, a.y, a.z, a.w, b.x, b.y, b.z, b.w, c4.x, c4.y};
            float r1[NUM_CLASSES] = {c4.z, c4.w, d.x, d.y, d.z, d.w, e.x, e.y, e.z, e.w};
            float nom0 = 0.f, nom1 = 0.f;
#pragma unroll
            for (int c = 0; c < NUM_CLASSES; ++c) {
                nom0 += r0[c] * w[c];
                nom1 += r1[c] * w[c];
                sumsq += r0[c] * r0[c] + r1[c] * r1[c];
            }
            sum_log += __logf(nom0) + __logf(nom1);
        }
    }

    // ---- phase 3: block reduce, write per-block partial (plain store) ----
    for (int off = 32; off > 0; off >>= 1) {
        sum_log += __shfl_down(sum_log, off, 64);
        sumsq += __shfl_down(sumsq, off, 64);
    }
    __shared__ float s1[4], s2[4];
    if (lane == 0) { s1[wave] = sum_log; s2[wave] = sumsq; }
    __syncthreads();
    if (threadIdx.x == 0) {
        float t1 = s1[0] + s1[1] + s1[2] + s1[3];
        float t2 = s2[0] + s2[1] + s2[2] + s2[3];
        pacc[blockIdx.x] = make_float2(t1, t2);
    }
}

__global__ void __launch_bounds__(256) finalize_kernel(const float2* __restrict__ pacc,
                                                       float* __restrict__ out, float fn) {
    float sum_log = 0.f, sumsq = 0.f;
    for (int i = threadIdx.x; i < B_BLOCKS; i += 256) {
        float2 v = pacc[i];
        sum_log += v.x;
        sumsq += v.y;
    }
    for (int off = 32; off > 0; off >>= 1) {
        sum_log += __shfl_down(sum_log, off, 64);
        sumsq += __shfl_down(sumsq, off, 64);
    }
    __shared__ float s1[4], s2[4];
    const int wave = threadIdx.x >> 6;
    if ((threadIdx.x & 63) == 0) { s1[wave] = sum_log; s2[wave] = sumsq; }
    __syncthreads();
    if (threadIdx.x == 0) {
        float t1 = s1[0] + s1[1] + s1[2] + s1[3];
        float t2 = s2[0] + s2[1] + s2[2] + s2[3];
        // mean(-log(nom/denom)) = 0.5*log(sumsq) + 0.5*log(N) - sum_log/N
        out[0] = 0.5f * logf(t2) + 0.5f * logf(fn) - t1 / fn;
    }
}

extern "C" void kernel_launch(void* const* d_in, const int* in_sizes, int n_in,
                              void* d_out, int out_size, void* d_ws, size_t ws_size,
                              hipStream_t stream) {
    const float* outputs = (const float*)d_in[0];
    const int* target = (const int*)d_in[1];
    const int n = in_sizes[1];

    unsigned int* pc = (unsigned int*)d_ws;
    float2* pacc = (float2*)((char*)d_ws + A_BLOCKS * NUM_CLASSES * sizeof(unsigned int));

    hist_kernel<<<A_BLOCKS, 256, 0, stream>>>(target, pc, n);
    main_kernel<<<B_BLOCKS, 256, 0, stream>>>(outputs, pc, pacc, n);
    finalize_kernel<<<1, 256, 0, stream>>>(pacc, (float*)d_out, (float)n);
}